// Round 3
// baseline (141.668 us; speedup 1.0000x reference)
//
#include <hip/hip_runtime.h>
#include <hip/hip_bf16.h>

// RBF: out[n][o] = exp(-max(||x_n||^2 - 2<x_n,c_o> + ||c_o||^2, 0) * exp(-2*ls_o))
// M=131072, K=128, O=512.  Memory-bound: 64MB read + 256MB write -> ~51us floor.
//
// Design: 512 blocks x 256 threads (4 waves), each block owns 256 x-rows.
// Each wave owns 128 output columns; its 128 centers are held in REGISTERS
// as bf16 MFMA fragments (loaded once per block from L2-resident centers).
// MFMA operands swapped (A=centers, B=x) so each lane's 4 acc regs are 4
// CONSECUTIVE output columns of one x-row -> float4 stores.
// Zero __syncthreads(); the only LDS is a per-wave csq/sigma table.

typedef __attribute__((ext_vector_type(8))) short bf16x8;
typedef __attribute__((ext_vector_type(4))) float f32x4;

#define KDIM 128
#define ODIM 512
#define ROWS_PER_BLOCK 256
#define TILE_ROWS 16
#define NTILES (ROWS_PER_BLOCK / TILE_ROWS)   // 16
#define GROUPS 8                               // 8 x 16 centers per wave

union BF8 { unsigned u[4]; bf16x8 v; };

// round-to-nearest-even fp32 -> bf16, packed pair
__device__ __forceinline__ unsigned pack_bf2(float a, float b) {
    unsigned ua = __builtin_bit_cast(unsigned, a);
    unsigned ub = __builtin_bit_cast(unsigned, b);
    ua += 0x7fffu + ((ua >> 16) & 1u);
    ub += 0x7fffu + ((ub >> 16) & 1u);
    return (ua >> 16) | (ub & 0xffff0000u);
}

__global__ __launch_bounds__(256, 2) void rbf_regc_kernel(
    const float* __restrict__ x,
    const float* __restrict__ centers,
    const float* __restrict__ log_sigmas,
    float* __restrict__ out)
{
    __shared__ float sA[ODIM];  // exp(-2*ls) per center
    __shared__ float sB[ODIM];  // csq * exp(-2*ls) per center

    const int t  = threadIdx.x;
    const int wv = t >> 6;            // wave 0..3 -> cols wv*128..+127
    const int l  = t & 63;
    const int lr = l & 15;            // fragment M/N index
    const int lk = l >> 4;            // fragment k-group
    const int c0 = wv * 128;

    // ---- prologue: this wave's 128 centers -> bf16 register fragments ----
    bf16x8 cfrag[GROUPS][4];
    #pragma unroll
    for (int g = 0; g < GROUPS; ++g) {
        int c = c0 + g * 16 + lr;
        const float* cp = centers + (size_t)c * KDIM + lk * 8;
        float csq = 0.f;
        #pragma unroll
        for (int kk = 0; kk < 4; ++kk) {
            const float4* p = (const float4*)(cp + kk * 32);
            float4 v0 = p[0], v1 = p[1];
            csq += v0.x*v0.x + v0.y*v0.y + v0.z*v0.z + v0.w*v0.w
                 + v1.x*v1.x + v1.y*v1.y + v1.z*v1.z + v1.w*v1.w;
            BF8 b;
            b.u[0] = pack_bf2(v0.x, v0.y);
            b.u[1] = pack_bf2(v0.z, v0.w);
            b.u[2] = pack_bf2(v1.x, v1.y);
            b.u[3] = pack_bf2(v1.z, v1.w);
            cfrag[g][kk] = b.v;
        }
        // lanes {l, l+16, l+32, l+48} hold the 4 k-quarters of center c
        csq += __shfl_xor(csq, 16);
        csq += __shfl_xor(csq, 32);
        if (l < 16) {
            float ls = log_sigmas[c];
            float a  = __expf(-2.0f * ls);   // 1/sigma^2
            sA[c] = a;
            sB[c] = csq * a;
        }
    }
    // no barrier needed: each wave reads only the sA/sB entries it wrote

    const int r0base = blockIdx.x * ROWS_PER_BLOCK;

    for (int tile = 0; tile < NTILES; ++tile) {
        const int r0 = r0base + tile * TILE_ROWS;

        // ---- load + convert x tile: lane holds row (r0+lr), k = kk*32+lk*8 ----
        const float* xp = x + (size_t)(r0 + lr) * KDIM + lk * 8;
        bf16x8 xfrag[4];
        float xsq = 0.f;
        #pragma unroll
        for (int kk = 0; kk < 4; ++kk) {
            const float4* p = (const float4*)(xp + kk * 32);
            float4 v0 = p[0], v1 = p[1];
            xsq += v0.x*v0.x + v0.y*v0.y + v0.z*v0.z + v0.w*v0.w
                 + v1.x*v1.x + v1.y*v1.y + v1.z*v1.z + v1.w*v1.w;
            BF8 b;
            b.u[0] = pack_bf2(v0.x, v0.y);
            b.u[1] = pack_bf2(v0.z, v0.w);
            b.u[2] = pack_bf2(v1.x, v1.y);
            b.u[3] = pack_bf2(v1.z, v1.w);
            xfrag[kk] = b.v;
        }
        xsq += __shfl_xor(xsq, 16);
        xsq += __shfl_xor(xsq, 32);   // every lane: ||x_{r0+lr}||^2

        // ---- MFMA: A=centers(M), B=x(N). D[center][xrow] ----
        f32x4 acc[GROUPS];
        #pragma unroll
        for (int g = 0; g < GROUPS; ++g) acc[g] = (f32x4){0.f, 0.f, 0.f, 0.f};
        #pragma unroll
        for (int g = 0; g < GROUPS; ++g) {
            #pragma unroll
            for (int kk = 0; kk < 4; ++kk)
                acc[g] = __builtin_amdgcn_mfma_f32_16x16x32_bf16(
                             cfrag[g][kk], xfrag[kk], acc[g], 0, 0, 0);
        }

        // ---- epilogue: lane owns x-row (r0+lr), centers cb..cb+3 per group ----
        float* orow = out + (size_t)(r0 + lr) * ODIM;
        #pragma unroll
        for (int g = 0; g < GROUPS; ++g) {
            const int cb = c0 + g * 16 + lk * 4;   // 4 consecutive centers
            float4 A4 = *(const float4*)&sA[cb];
            float4 B4 = *(const float4*)&sB[cb];
            float4 r;
            float t0;
            t0  = fmaf(A4.x, fmaf(-2.0f, acc[g][0], xsq), B4.x);
            r.x = __expf(-fmaxf(t0, 0.0f));
            t0  = fmaf(A4.y, fmaf(-2.0f, acc[g][1], xsq), B4.y);
            r.y = __expf(-fmaxf(t0, 0.0f));
            t0  = fmaf(A4.z, fmaf(-2.0f, acc[g][2], xsq), B4.z);
            r.z = __expf(-fmaxf(t0, 0.0f));
            t0  = fmaf(A4.w, fmaf(-2.0f, acc[g][3], xsq), B4.w);
            r.w = __expf(-fmaxf(t0, 0.0f));
            *(float4*)(orow + cb) = r;
        }
    }
}

extern "C" void kernel_launch(void* const* d_in, const int* in_sizes, int n_in,
                              void* d_out, int out_size, void* d_ws, size_t ws_size,
                              hipStream_t stream) {
    const float* x          = (const float*)d_in[0];
    const float* centers    = (const float*)d_in[1];
    const float* log_sigmas = (const float*)d_in[2];
    float* out = (float*)d_out;

    const int n_rows = in_sizes[0] / KDIM;            // 131072
    const int grid   = n_rows / ROWS_PER_BLOCK;       // 512
    rbf_regc_kernel<<<grid, 256, 0, stream>>>(x, centers, log_sigmas, out);
}

// Round 4
// 88.556 us; speedup vs baseline: 1.5998x; 1.5998x over previous
//
#include <hip/hip_runtime.h>
#include <hip/hip_bf16.h>

// RBF: out[n][o] = exp(-max(||x_n||^2 - 2<x_n,c_o> + ||c_o||^2, 0) * exp(-2*ls_o))
// M=131072, K=128, O=512.  Memory-bound: 67MB read + 268MB write -> ~51us floor.
//
// Round-3 design:
//  * grid = 256 blocks (exactly 1 per CU), 1024 threads (16 waves), 512 rows/block.
//  * ALL 512 centers staged ONCE per CU into 128 KiB LDS (bf16, XOR-swizzled),
//    csq/sigma folded into two 512-entry tables. ONE barrier total.
//  * Each wave then independently streams 2 x 16-row tiles: x -> bf16 register
//    fragments, MFMA A=centers(LDS)/B=x so each lane's 4 accs are 4 CONSECUTIVE
//    output columns of one row -> float4 stores. A-frags reused across both
//    tiles (halves LDS read traffic).
//  * No barriers in the main loop; 4 waves/SIMD hide store backpressure.

typedef __attribute__((ext_vector_type(8))) short bf16x8;
typedef __attribute__((ext_vector_type(4))) float f32x4;

#define KDIM 128
#define ODIM 512
#define BLOCK_ROWS 512   // rows per block
#define NGROUPS 32       // 32 groups of 16 centers

union BF8 { unsigned u[4]; bf16x8 v; };

// round-to-nearest-even fp32 -> bf16, packed pair
__device__ __forceinline__ unsigned pack_bf2(float a, float b) {
    unsigned ua = __builtin_bit_cast(unsigned, a);
    unsigned ub = __builtin_bit_cast(unsigned, b);
    ua += 0x7fffu + ((ua >> 16) & 1u);
    ub += 0x7fffu + ((ub >> 16) & 1u);
    return (ua >> 16) | (ub & 0xffff0000u);
}

__global__ __launch_bounds__(1024, 1) void rbf_kernel(
    const float* __restrict__ x,
    const float* __restrict__ centers,
    const float* __restrict__ log_sigmas,
    float* __restrict__ out)
{
    __shared__ uint4 sC[ODIM * 16];   // 512 centers x 128 bf16, swizzled (128 KiB)
    __shared__ float sIS[ODIM];       // exp(-2*ls)
    __shared__ float sCS[ODIM];       // csq * exp(-2*ls)

    const int t  = threadIdx.x;       // 0..1023
    const int w  = t >> 6;            // wave 0..15
    const int l  = t & 63;
    const int lr = l & 15;            // fragment M/N index
    const int lk = l >> 4;            // fragment k-group

    // ---- stage ALL centers: fp32 -> bf16 + fused csq/sigma tables ----
    #pragma unroll
    for (int i = 0; i < 8; ++i) {
        int c    = i * 1024 + t;      // 8192 chunks of 8 floats
        int row  = c >> 4;            // center 0..511
        int col8 = c & 15;            // 8-float chunk within center
        const float4* gp = (const float4*)(centers + (size_t)row * KDIM + col8 * 8);
        float4 v0 = gp[0], v1 = gp[1];
        float s = v0.x*v0.x + v0.y*v0.y + v0.z*v0.z + v0.w*v0.w
                + v1.x*v1.x + v1.y*v1.y + v1.z*v1.z + v1.w*v1.w;
        s += __shfl_xor(s, 1); s += __shfl_xor(s, 2);
        s += __shfl_xor(s, 4); s += __shfl_xor(s, 8);
        uint4 wv = { pack_bf2(v0.x, v0.y), pack_bf2(v0.z, v0.w),
                     pack_bf2(v1.x, v1.y), pack_bf2(v1.z, v1.w) };
        int byte = row * 256 + col8 * 16;
        byte ^= (row & 7) << 4;
        *(uint4*)((char*)sC + byte) = wv;
        if ((t & 15) == 0) {
            float a = __expf(-2.0f * log_sigmas[row]);  // 1/sigma^2
            sIS[row] = a;
            sCS[row] = s * a;
        }
    }
    __syncthreads();   // the only barrier in the kernel

    // ---- this wave's 32 x-rows -> bf16 register fragments (2 tiles) ----
    const int r0 = blockIdx.x * BLOCK_ROWS + w * 32;
    bf16x8 xf[2][4];
    float  xsq[2];
    #pragma unroll
    for (int tt = 0; tt < 2; ++tt) {
        const float* xp = x + (size_t)(r0 + tt * 16 + lr) * KDIM + lk * 8;
        float s = 0.f;
        #pragma unroll
        for (int kk = 0; kk < 4; ++kk) {
            const float4* p = (const float4*)(xp + kk * 32);
            float4 v0 = p[0], v1 = p[1];
            s += v0.x*v0.x + v0.y*v0.y + v0.z*v0.z + v0.w*v0.w
               + v1.x*v1.x + v1.y*v1.y + v1.z*v1.z + v1.w*v1.w;
            BF8 b;
            b.u[0] = pack_bf2(v0.x, v0.y);
            b.u[1] = pack_bf2(v0.z, v0.w);
            b.u[2] = pack_bf2(v1.x, v1.y);
            b.u[3] = pack_bf2(v1.w == v1.w ? v1.z : v1.z, v1.w);  // plain pack
            b.u[3] = pack_bf2(v1.z, v1.w);
            xf[tt][kk] = b.v;
        }
        // lanes {lr, lr+16, lr+32, lr+48} hold the 4 k-quarters of one row
        s += __shfl_xor(s, 16);
        s += __shfl_xor(s, 32);
        xsq[tt] = s;
    }

    float* orow0 = out + (size_t)(r0 + lr) * ODIM;
    float* orow1 = out + (size_t)(r0 + 16 + lr) * ODIM;

    // ---- main loop: 32 groups of 16 centers; A-frag reused for both tiles ----
    #pragma unroll 2
    for (int g = 0; g < NGROUPS; ++g) {
        bf16x8 af[4];
        #pragma unroll
        for (int kk = 0; kk < 4; ++kk) {
            int row  = g * 16 + lr;
            int byte = row * 256 + kk * 64 + lk * 16;
            byte ^= (row & 7) << 4;
            af[kk] = *(const bf16x8*)((const char*)sC + byte);
        }
        f32x4 a0 = (f32x4){0.f, 0.f, 0.f, 0.f};
        f32x4 a1 = (f32x4){0.f, 0.f, 0.f, 0.f};
        #pragma unroll
        for (int kk = 0; kk < 4; ++kk) {
            a0 = __builtin_amdgcn_mfma_f32_16x16x32_bf16(af[kk], xf[0][kk], a0, 0, 0, 0);
            a1 = __builtin_amdgcn_mfma_f32_16x16x32_bf16(af[kk], xf[1][kk], a1, 0, 0, 0);
        }
        // lane owns centers cb..cb+3 (consecutive), x-rows (r0+lr) and (r0+16+lr)
        const int cb = g * 16 + lk * 4;
        float4 A4 = *(const float4*)&sIS[cb];
        float4 B4 = *(const float4*)&sCS[cb];
        float4 o0, o1;
        o0.x = __expf(-fmaxf(fmaf(A4.x, fmaf(-2.f, a0[0], xsq[0]), B4.x), 0.f));
        o0.y = __expf(-fmaxf(fmaf(A4.y, fmaf(-2.f, a0[1], xsq[0]), B4.y), 0.f));
        o0.z = __expf(-fmaxf(fmaf(A4.z, fmaf(-2.f, a0[2], xsq[0]), B4.z), 0.f));
        o0.w = __expf(-fmaxf(fmaf(A4.w, fmaf(-2.f, a0[3], xsq[0]), B4.w), 0.f));
        o1.x = __expf(-fmaxf(fmaf(A4.x, fmaf(-2.f, a1[0], xsq[1]), B4.x), 0.f));
        o1.y = __expf(-fmaxf(fmaf(A4.y, fmaf(-2.f, a1[1], xsq[1]), B4.y), 0.f));
        o1.z = __expf(-fmaxf(fmaf(A4.z, fmaf(-2.f, a1[2], xsq[1]), B4.z), 0.f));
        o1.w = __expf(-fmaxf(fmaf(A4.w, fmaf(-2.f, a1[3], xsq[1]), B4.w), 0.f));
        *(float4*)(orow0 + cb) = o0;
        *(float4*)(orow1 + cb) = o1;
    }
}

extern "C" void kernel_launch(void* const* d_in, const int* in_sizes, int n_in,
                              void* d_out, int out_size, void* d_ws, size_t ws_size,
                              hipStream_t stream) {
    const float* x          = (const float*)d_in[0];
    const float* centers    = (const float*)d_in[1];
    const float* log_sigmas = (const float*)d_in[2];
    float* out = (float*)d_out;

    const int n_rows = in_sizes[0] / KDIM;          // 131072
    const int grid   = n_rows / BLOCK_ROWS;         // 256 blocks = 1 per CU
    rbf_kernel<<<grid, 1024, 0, stream>>>(x, centers, log_sigmas, out);
}